// Round 21
// baseline (79.653 us; speedup 1.0000x reference)
//
#include <hip/hip_runtime.h>
#include <hip/hip_bf16.h>
#include <math.h>

#define VOCAB 2048
#define EMB 256
#define MAXLEN 8
#define NBATCH 16
#define LAT 16

typedef unsigned short u16;
typedef unsigned int u32;
using bf16x8 = __attribute__((ext_vector_type(8))) short;
using f32x4  = __attribute__((ext_vector_type(4))) float;

// token = argmax_j ( j/2048 <= v && v <= (j+1)/2048 ), 0 if none.
// cumsum of uniform softmax is exactly k/2048 in fp32; v*2048 is exact.
__device__ __forceinline__ int token_of(float v) {
    float u = v * 2048.0f;
    if (!(u >= 0.0f) || u > 2048.0f) return 0;   // v<0, v>1, or NaN
    int k = (int)ceilf(u) - 1;
    return k < 0 ? 0 : k;
}

__device__ __forceinline__ float sigmoidf_(float x) { return 1.0f / (1.0f + expf(-x)); }

__device__ __forceinline__ u16 to_bf16(float x) {
    __hip_bfloat16 hb = __float2bfloat16(x);   // RTNE
    return *reinterpret_cast<u16*>(&hb);
}

// ---------------------------------------------------------------------------
// GATE-INTERLEAVED column packing: packed col c = u*4 + g  (u=c>>2, g=c&3).
// One 16-col MFMA ntile = 4 u's x 4 gates -> LSTM update is block-local,
// enabling 512 independent blocks (full chip) in the recurrent step.
// Fragment (l,i) of (nt,k0): bf16( W[(k0*32 + 8*(l>>4) + i)*8192 + gcol ] ),
// gcol = ((l&15)&3)*2048 + nt*4 + ((l&15)>>2). A-frags use the same k-map,
// so any in-fragment k-permutation cancels.
// PACK cost is structural (~33 us): a transpose forces one HBM side to
// <=512B-granular access; 6 variants (rounds 14-20) all ~33. Using the
// round-16 core (best absmax margin). step0 is folded in as independent
// blocks; the xz GEMM is inlined into the step kernels (1 MFMA/wave).
// ---------------------------------------------------------------------------

// ---- K1: [0,4608): W pack; [4608,4624): XA pack; [4624,5136): step0.
__global__ __launch_bounds__(256) void k_pack(
        const float* __restrict__ Wr, const float* __restrict__ Wk,
        const float* __restrict__ ip, const float* __restrict__ E,
        const float* __restrict__ bv,
        u16* __restrict__ BW, u16* __restrict__ BWk, u16* __restrict__ XA,
        float* __restrict__ H, float* __restrict__ c, u16* __restrict__ hA1) {
    __shared__ __align__(16) char smem[13312];
    int bx = blockIdx.x;
    int tid = threadIdx.x;
    if (bx < 4608) {
        // ================= weight pack (round-16 core) =================
        u16 (*lds)[128] = (u16(*)[128])smem;     // 32 x 128 u16
        const float* W; u16* dst; int kc, uc, nk0;
        if (bx < 4096) { W = Wr; dst = BW;  kc = bx >> 6;          uc = bx & 63; nk0 = 64; }
        else           { W = Wk; dst = BWk; kc = (bx - 4096) >> 6; uc = (bx - 4096) & 63; nk0 = 8; }

        #pragma unroll
        for (int it = 0; it < 2; ++it) {
            int lin = it * 256 + tid;        // 0..511
            int r = lin >> 4;                // 0..31
            int grp = lin & 15;              // 0..15
            const float* base = W + (size_t)(kc * 32 + r) * 8192 + uc * 32 + grp * 2;
            float2 v0 = *(const float2*)(base + 0 * 2048);
            float2 v1 = *(const float2*)(base + 1 * 2048);
            float2 v2 = *(const float2*)(base + 2 * 2048);
            float2 v3 = *(const float2*)(base + 3 * 2048);
            u16 o[8] = {to_bf16(v0.x), to_bf16(v1.x), to_bf16(v2.x), to_bf16(v3.x),
                        to_bf16(v0.y), to_bf16(v1.y), to_bf16(v2.y), to_bf16(v3.y)};
            *(uint4*)&lds[r][grp * 8] = *(uint4*)o;
        }
        __syncthreads();

        int w = tid >> 6, l = tid & 63;
        #pragma unroll
        for (int q = 0; q < 2; ++q) {
            int nt_l = q * 4 + w;
            u16 o[8];
            #pragma unroll
            for (int i = 0; i < 8; ++i) o[i] = lds[8 * (l >> 4) + i][nt_l * 16 + (l & 15)];
            int nt = uc * 8 + nt_l;
            *(uint4*)(dst + ((size_t)(nt * nk0 + kc) * 64 + l) * 8) = *(uint4*)o;
        }
    } else if (bx < 4624) {
        // ================= XA pack =================
        int gidx = (bx - 4608) * 256 + tid;   // 0..4095
        int l = gidx & 63;
        int k0 = (gidx >> 6) & 7;
        int t = gidx >> 9;
        int b = l & 15;
        int tok = token_of(ip[b * LAT + t]);
        const float* s = E + (size_t)tok * EMB + k0 * 32 + 8 * (l >> 4);
        u16 o[8];
        #pragma unroll
        for (int i = 0; i < 8; ++i) o[i] = to_bf16(s[i]);
        *(uint4*)(XA + (size_t)gidx * 8) = *(uint4*)o;
    } else {
        // ================= step0 (h=c=0): z0 = bias + X[0]@Wk =================
        int sb = bx - 4624;                       // 0..511
        int nt = (sb & 7) * 64 + (sb >> 3);       // XCD swizzle
        u16 (*wk)[18] = (u16(*)[18])smem;         // 256 x 18 u16 (padded)
        float (*zsh0)[256] = (float(*)[256])(smem + 9216);
        int w = tid >> 6, l = tid & 63;

        #pragma unroll
        for (int it = 0; it < 4; ++it) {
            int lin = it * 256 + tid;
            int k = lin >> 2, g = lin & 3;
            float4 v = *(const float4*)&Wk[(size_t)k * 8192 + g * 2048 + nt * 4];
            wk[k][0 * 4 + g] = to_bf16(v.x);
            wk[k][1 * 4 + g] = to_bf16(v.y);
            wk[k][2 * 4 + g] = to_bf16(v.z);
            wk[k][3 * 4 + g] = to_bf16(v.w);
        }
        __syncthreads();

        int n = l & 15;
        f32x4 acc = {0.f, 0.f, 0.f, 0.f};
        if (w == 0) {
            float bias = bv[(n & 3) * 2048 + nt * 4 + (n >> 2)];
            acc[0] = bias; acc[1] = bias; acc[2] = bias; acc[3] = bias;
        }
        int tok = token_of(ip[n * LAT + 0]);
        const float* er = E + (size_t)tok * EMB + 8 * (l >> 4);
        #pragma unroll
        for (int q = 0; q < 2; ++q) {
            int s = w * 2 + q;
            u16 bo[8];
            #pragma unroll
            for (int i = 0; i < 8; ++i) bo[i] = wk[s * 32 + 8 * (l >> 4) + i][n];
            float4 e0 = *(const float4*)(er + s * 32);
            float4 e1 = *(const float4*)(er + s * 32 + 4);
            u16 ao[8] = {to_bf16(e0.x), to_bf16(e0.y), to_bf16(e0.z), to_bf16(e0.w),
                         to_bf16(e1.x), to_bf16(e1.y), to_bf16(e1.z), to_bf16(e1.w)};
            acc = __builtin_amdgcn_mfma_f32_16x16x32_bf16(*(bf16x8*)ao, *(bf16x8*)bo, acc, 0, 0, 0);
        }
        #pragma unroll
        for (int i = 0; i < 4; ++i)
            zsh0[w][(4 * (l >> 4) + i) * 16 + n] = acc[i];
        __syncthreads();

        if (tid < 64) {
            int b = tid >> 2, ul = tid & 3;
            int myu = nt * 4 + ul;
            float z0 = 0.f, z2 = 0.f, z3 = 0.f;
            #pragma unroll
            for (int ww = 0; ww < 4; ++ww) {
                z0 += zsh0[ww][b * 16 + ul * 4 + 0];
                z2 += zsh0[ww][b * 16 + ul * 4 + 2];
                z3 += zsh0[ww][b * 16 + ul * 4 + 3];
            }
            float cn = sigmoidf_(z0) * tanhf(z2);
            float hn = sigmoidf_(z3) * tanhf(cn);
            int tok0 = token_of(ip[b * LAT + 0]);
            float hw = tok0 != 0 ? hn : 0.0f;
            float cw = tok0 != 0 ? cn : 0.0f;
            c[b * 2048 + myu] = cw;
            H[b * 2048 + myu] = hw;
            u16 own = to_bf16(hw);
            int pair = __shfl_xor((int)own, 1);
            if (!(ul & 1)) {
                u32 val = (u32)own | ((u32)(u16)pair << 16);
                int k0 = myu >> 5, lg = (myu >> 3) & 3, i = myu & 7;
                *((u32*)hA1 + ((((k0 * 64) + lg * 16 + b) * 8 + i) >> 1)) = val;
            }
        }
    }
}

// ---- K2: fused step t. 512 blocks x 512 thr = 8 waves (K-eighths).
// Inline xz: wave kq adds XA[t][kq] x BWk[nt][kq]; bias in wave 0's acc-init.
__global__ __launch_bounds__(512) void k_step(
        const u16* __restrict__ BW, const u16* __restrict__ BWk,
        const u16* __restrict__ XA, const float* __restrict__ bv,
        const u16* __restrict__ hAin, u16* __restrict__ hAout,
        const float* __restrict__ ip, float* __restrict__ c,
        float* __restrict__ H, int t) {
    int j = blockIdx.x;
    int nt = (j & 7) * 64 + (j >> 3);
    int tid = threadIdx.x;
    int kq = tid >> 6, l = tid & 63;     // kq = K-eighth (0..7)
    __shared__ float zsh[8][256];

    const bf16x8* ap = (const bf16x8*)(hAin + ((size_t)(kq * 8) * 64 + l) * 8);
    const bf16x8* bp = (const bf16x8*)(BW + (((size_t)(nt * 64) + kq * 8) * 64 + l) * 8);
    bf16x8 xa = *(const bf16x8*)(XA + ((size_t)(t * 8 + kq) * 64 + l) * 8);
    bf16x8 xb = *(const bf16x8*)(BWk + ((size_t)(nt * 8 + kq) * 64 + l) * 8);
    bf16x8 ar[8], br[8];
    #pragma unroll
    for (int i = 0; i < 8; ++i) { ar[i] = ap[i * 64]; br[i] = bp[i * 64]; }

    f32x4 acc = {0.f, 0.f, 0.f, 0.f};
    if (kq == 0) {
        int n = l & 15;
        float bias = bv[(n & 3) * 2048 + nt * 4 + (n >> 2)];
        acc[0] = bias; acc[1] = bias; acc[2] = bias; acc[3] = bias;
    }
    acc = __builtin_amdgcn_mfma_f32_16x16x32_bf16(xa, xb, acc, 0, 0, 0);
    #pragma unroll
    for (int s = 0; s < 8; ++s)
        acc = __builtin_amdgcn_mfma_f32_16x16x32_bf16(ar[s], br[s], acc, 0, 0, 0);

    #pragma unroll
    for (int i = 0; i < 4; ++i)
        zsh[kq][(4 * (l >> 4) + i) * 16 + (l & 15)] = acc[i];
    __syncthreads();

    if (tid < 64) {
        int b = tid >> 2, ul = tid & 3;
        int myu = nt * 4 + ul;
        float z[4] = {0.f, 0.f, 0.f, 0.f};
        #pragma unroll
        for (int kk = 0; kk < 8; ++kk) {
            float4 zv = *(const float4*)&zsh[kk][b * 16 + ul * 4];
            z[0] += zv.x; z[1] += zv.y; z[2] += zv.z; z[3] += zv.w;
        }
        int idx = b * 2048 + myu;
        float co = c[idx];
        float ho = H[((size_t)(t - 1) * 16 + b) * 2048 + myu];
        float cn = sigmoidf_(z[1]) * co + sigmoidf_(z[0]) * tanhf(z[2]);
        float hn = sigmoidf_(z[3]) * tanhf(cn);
        int tok = token_of(ip[b * LAT + t]);
        float hw = tok != 0 ? hn : ho;
        float cw = tok != 0 ? cn : co;
        c[idx] = cw;
        H[((size_t)t * 16 + b) * 2048 + myu] = hw;
        u16 own = to_bf16(hw);
        int pair = __shfl_xor((int)own, 1);
        if (!(ul & 1)) {
            u32 val = (u32)own | ((u32)(u16)pair << 16);
            int k0 = myu >> 5, lg = (myu >> 3) & 3, i = myu & 7;
            *((u32*)hAout + ((((k0 * 64) + lg * 16 + b) * 8 + i) >> 1)) = val;
        }
    }
}

// ---- K3: softmax of all 128 recorded h rows -> d_out[b][t][:] ----
__global__ __launch_bounds__(256) void k_softmax(const float* __restrict__ H,
                                                 float* __restrict__ out) {
    int r = blockIdx.x;          // r = t*16 + b
    int t = r >> 4, b = r & 15;
    int tid = threadIdx.x;
    const float* hr = H + (size_t)r * VOCAB;
    float v[8];
    float m = -1e30f;
    #pragma unroll
    for (int i = 0; i < 8; ++i) { v[i] = hr[tid + i * 256]; m = fmaxf(m, v[i]); }

    __shared__ float redm[4], reds[4];
    int wid = tid >> 6, lane = tid & 63;
    #pragma unroll
    for (int off = 32; off; off >>= 1) m = fmaxf(m, __shfl_down(m, off));
    if (lane == 0) redm[wid] = m;
    __syncthreads();
    m = fmaxf(fmaxf(redm[0], redm[1]), fmaxf(redm[2], redm[3]));

    float e[8];
    float s = 0.0f;
    #pragma unroll
    for (int i = 0; i < 8; ++i) { e[i] = expf(v[i] - m); s += e[i]; }
    #pragma unroll
    for (int off = 32; off; off >>= 1) s += __shfl_down(s, off);
    if (lane == 0) reds[wid] = s;
    __syncthreads();
    s = reds[0] + reds[1] + reds[2] + reds[3];

    float* o = out + ((size_t)b * MAXLEN + t) * VOCAB;
    #pragma unroll
    for (int i = 0; i < 8; ++i) o[tid + i * 256] = e[i] / s;
}

extern "C" void kernel_launch(void* const* d_in, const int* in_sizes, int n_in,
                              void* d_out, int out_size, void* d_ws, size_t ws_size,
                              hipStream_t stream) {
    const float* ip = (const float*)d_in[0];   // (16,16)
    const float* E  = (const float*)d_in[1];   // (2048,256)
    const float* Wk = (const float*)d_in[2];   // (256,8192)
    const float* Wr = (const float*)d_in[3];   // (2048,8192)
    const float* bv = (const float*)d_in[4];   // (8192,)

    char* w = (char*)d_ws;
    float* H   = (float*)w;  w += (size_t)262144 * 4;                  // 1 MB
    float* c   = (float*)w;  w += (size_t)32768 * 4;                   // 128 KB
    u16* XA  = (u16*)w;      w += (size_t)32768 * 2;                   // 64 KB
    u16* hA0 = (u16*)w;      w += (size_t)32768 * 2;
    u16* hA1 = (u16*)w;      w += (size_t)32768 * 2;
    u16* BWk = (u16*)w;      w += (size_t)2097152 * 2;                 // 4 MB
    u16* BW  = (u16*)w;      w += (size_t)16777216 * 2;                // 32 MB

    k_pack<<<5136, 256, 0, stream>>>(Wr, Wk, ip, E, bv, BW, BWk, XA, H, c, hA1);
    u16* hAbuf[2] = {hA0, hA1};
    for (int t = 1; t < MAXLEN; ++t)
        k_step<<<512, 512, 0, stream>>>(BW, BWk, XA, bv, hAbuf[t & 1], hAbuf[(t + 1) & 1],
                                        ip, c, H, t);
    k_softmax<<<128, 256, 0, stream>>>(H, (float*)d_out);
}

// Round 22
// 69.756 us; speedup vs baseline: 1.1419x; 1.1419x over previous
//
#include <hip/hip_runtime.h>
#include <hip/hip_bf16.h>
#include <math.h>

#define VOCAB 2048
#define EMB 256
#define MAXLEN 8
#define NBATCH 16
#define LAT 16

typedef unsigned short u16;
typedef unsigned int u32;
using bf16x8 = __attribute__((ext_vector_type(8))) short;
using f32x4  = __attribute__((ext_vector_type(4))) float;

// token = argmax_j ( j/2048 <= v && v <= (j+1)/2048 ), 0 if none.
// cumsum of uniform softmax is exactly k/2048 in fp32; v*2048 is exact.
__device__ __forceinline__ int token_of(float v) {
    float u = v * 2048.0f;
    if (!(u >= 0.0f) || u > 2048.0f) return 0;   // v<0, v>1, or NaN
    int k = (int)ceilf(u) - 1;
    return k < 0 ? 0 : k;
}

__device__ __forceinline__ float sigmoidf_(float x) { return 1.0f / (1.0f + expf(-x)); }

__device__ __forceinline__ u16 to_bf16(float x) {
    __hip_bfloat16 hb = __float2bfloat16(x);   // RTNE
    return *reinterpret_cast<u16*>(&hb);
}

// ---------------------------------------------------------------------------
// GATE-INTERLEAVED column packing: packed col c = u*4 + g  (u=c>>2, g=c&3).
// One 16-col MFMA ntile = 4 u's x 4 gates -> LSTM update is block-local,
// enabling 512 independent blocks (full chip) in the recurrent step.
// Fragment (l,i) of (nt,k0): bf16( W[(k0*32 + 8*(l>>4) + i)*8192 + gcol ] ),
// gcol = ((l&15)&3)*2048 + nt*4 + ((l&15)>>2). A-frags use the same k-map,
// so any in-fragment k-permutation cancels.
// PACK wall theory (r21): VMEM-instruction ISSUE, not DRAM granularity/banks
// (6 variants ~33 us; DS-count cut was null in r20). 10 VMEM/thread x 2cyc
// issue ~ 38 us. This round: float4 fill -> 6 VMEM/thread, LDS contents
// bit-identical to round 16, assemble untouched.
// ---------------------------------------------------------------------------

// ---- K1: one-launch pack. [0,4096): Wr->BW; [4096,4608): Wk->BWk;
// [4608,4624): XA = E[token] A-fragments.
__global__ __launch_bounds__(256) void k_pack(
        const float* __restrict__ Wr, const float* __restrict__ Wk,
        const float* __restrict__ ip, const float* __restrict__ E,
        u16* __restrict__ BW, u16* __restrict__ BWk, u16* __restrict__ XA) {
    __shared__ __align__(16) u16 lds[32][128];   // 8 KB [row][packed_col_local]
    int bx = blockIdx.x;
    int tid = threadIdx.x;
    if (bx < 4608) {
        const float* W; u16* dst; int kc, uc, nk0;
        if (bx < 4096) { W = Wr; dst = BW;  kc = bx >> 6;          uc = bx & 63; nk0 = 64; }
        else           { W = Wk; dst = BWk; kc = (bx - 4096) >> 6; uc = (bx - 4096) & 63; nk0 = 8; }

        // fill: ONE item/thread (r = tid>>3, grp2 = tid&7): float4 per gate
        // (4 VMEM loads), 16 bf16 = packed cols grp2*16..+15 -> 2x b128.
        {
            int r = tid >> 3;                // 0..31
            int grp2 = tid & 7;              // 0..7
            const float* base = W + (size_t)(kc * 32 + r) * 8192 + uc * 32 + grp2 * 4;
            float4 v0 = *(const float4*)(base + 0 * 2048);
            float4 v1 = *(const float4*)(base + 1 * 2048);
            float4 v2 = *(const float4*)(base + 2 * 2048);
            float4 v3 = *(const float4*)(base + 3 * 2048);
            u16 o[16] = {to_bf16(v0.x), to_bf16(v1.x), to_bf16(v2.x), to_bf16(v3.x),
                         to_bf16(v0.y), to_bf16(v1.y), to_bf16(v2.y), to_bf16(v3.y),
                         to_bf16(v0.z), to_bf16(v1.z), to_bf16(v2.z), to_bf16(v3.z),
                         to_bf16(v0.w), to_bf16(v1.w), to_bf16(v2.w), to_bf16(v3.w)};
            *(uint4*)&lds[r][grp2 * 16]     = *(uint4*)&o[0];
            *(uint4*)&lds[r][grp2 * 16 + 8] = *(uint4*)&o[8];
        }
        __syncthreads();

        // assemble: 8 fragments (nt_l 0..7), 2 per thread, 16B coalesced stores
        int w = tid >> 6, l = tid & 63;
        #pragma unroll
        for (int q = 0; q < 2; ++q) {
            int nt_l = q * 4 + w;
            u16 o[8];
            #pragma unroll
            for (int i = 0; i < 8; ++i) o[i] = lds[8 * (l >> 4) + i][nt_l * 16 + (l & 15)];
            int nt = uc * 8 + nt_l;
            *(uint4*)(dst + ((size_t)(nt * nk0 + kc) * 64 + l) * 8) = *(uint4*)o;
        }
    } else {
        int gidx = (bx - 4608) * 256 + tid;   // 0..4095
        int l = gidx & 63;
        int k0 = (gidx >> 6) & 7;
        int t = gidx >> 9;
        int b = l & 15;
        int tok = token_of(ip[b * LAT + t]);
        const float* s = E + (size_t)tok * EMB + k0 * 32 + 8 * (l >> 4);
        u16 o[8];
        #pragma unroll
        for (int i = 0; i < 8; ++i) o[i] = to_bf16(s[i]);
        *(uint4*)(XA + (size_t)gidx * 8) = *(uint4*)o;
    }
}

// ---- K2: xz GEMM for all 8 t (into xz[t][nt][b][n]) + fused step0.
// 512 blocks x 256 thr; wave w handles t = 2w, 2w+1. Block owns ntile nt.
__global__ __launch_bounds__(256) void k_xzmm0(
        const u16* __restrict__ BWk, const u16* __restrict__ XA,
        const float* __restrict__ bv, const float* __restrict__ ip,
        float* __restrict__ xz, float* __restrict__ H,
        float* __restrict__ c, u16* __restrict__ hA1) {
    int j = blockIdx.x;
    int nt = (j & 7) * 64 + (j >> 3);
    int tid = threadIdx.x;
    int w = tid >> 6, l = tid & 63;
    __shared__ float zsh0[256];

    int n = l & 15;
    float bias = bv[(n & 3) * 2048 + nt * 4 + (n >> 2)];

    const bf16x8* bp = (const bf16x8*)(BWk + ((size_t)(nt * 8) * 64 + l) * 8);
    bf16x8 bw[8];
    #pragma unroll
    for (int s = 0; s < 8; ++s) bw[s] = bp[s * 64];

    #pragma unroll
    for (int q = 0; q < 2; ++q) {
        int t = w * 2 + q;
        const bf16x8* ap = (const bf16x8*)(XA + ((size_t)(t * 8) * 64 + l) * 8);
        f32x4 acc = {bias, bias, bias, bias};
        #pragma unroll
        for (int s = 0; s < 8; ++s)
            acc = __builtin_amdgcn_mfma_f32_16x16x32_bf16(ap[s * 64], bw[s], acc, 0, 0, 0);
        #pragma unroll
        for (int i = 0; i < 4; ++i) {
            int b = 4 * (l >> 4) + i;   // D row = batch (m89-verified C/D layout)
            xz[(((size_t)t * 512 + nt) * 16 + b) * 16 + n] = acc[i];
            if (t == 0) zsh0[b * 16 + n] = acc[i];
        }
    }
    __syncthreads();

    // step0 update (h=c=0) for this block's 4 u's x 16 batches
    if (tid < 64) {
        int b = tid >> 2, ul = tid & 3;
        int myu = nt * 4 + ul;
        float z0 = zsh0[b * 16 + ul * 4 + 0];
        float z2 = zsh0[b * 16 + ul * 4 + 2];
        float z3 = zsh0[b * 16 + ul * 4 + 3];
        float cn = sigmoidf_(z0) * tanhf(z2);
        float hn = sigmoidf_(z3) * tanhf(cn);
        int tok = token_of(ip[b * LAT + 0]);
        float hw = tok != 0 ? hn : 0.0f;
        float cw = tok != 0 ? cn : 0.0f;
        c[b * 2048 + myu] = cw;
        H[b * 2048 + myu] = hw;
        u16 own = to_bf16(hw);
        int pair = __shfl_xor((int)own, 1);
        if (!(ul & 1)) {
            u32 val = (u32)own | ((u32)(u16)pair << 16);
            int k0 = myu >> 5, lg = (myu >> 3) & 3, i = myu & 7;
            *((u32*)hA1 + ((((k0 * 64) + lg * 16 + b) * 8 + i) >> 1)) = val;
        }
    }
}

// ---- K3: fused step t. 512 blocks x 512 thr = 8 waves (K-eighths).
__global__ __launch_bounds__(512) void k_step(
        const u16* __restrict__ BW,
        const u16* __restrict__ hAin, u16* __restrict__ hAout,
        const float* __restrict__ xz, const float* __restrict__ ip,
        float* __restrict__ c, float* __restrict__ H, int t) {
    int j = blockIdx.x;
    int nt = (j & 7) * 64 + (j >> 3);
    int tid = threadIdx.x;
    int kq = tid >> 6, l = tid & 63;     // kq = K-eighth (0..7)
    __shared__ float zsh[8][256];

    const bf16x8* ap = (const bf16x8*)(hAin + ((size_t)(kq * 8) * 64 + l) * 8);
    const bf16x8* bp = (const bf16x8*)(BW + (((size_t)(nt * 64) + kq * 8) * 64 + l) * 8);
    bf16x8 ar[8], br[8];
    #pragma unroll
    for (int i = 0; i < 8; ++i) { ar[i] = ap[i * 64]; br[i] = bp[i * 64]; }

    f32x4 acc = {0.f, 0.f, 0.f, 0.f};
    #pragma unroll
    for (int s = 0; s < 8; ++s)
        acc = __builtin_amdgcn_mfma_f32_16x16x32_bf16(ar[s], br[s], acc, 0, 0, 0);

    #pragma unroll
    for (int i = 0; i < 4; ++i)
        zsh[kq][(4 * (l >> 4) + i) * 16 + (l & 15)] = acc[i];
    __syncthreads();

    if (tid < 64) {
        int b = tid >> 2, ul = tid & 3;
        int myu = nt * 4 + ul;
        float4 xv = *(const float4*)&xz[(((size_t)t * 512 + nt) * 16 + b) * 16 + ul * 4];
        float z[4] = {xv.x, xv.y, xv.z, xv.w};
        #pragma unroll
        for (int kk = 0; kk < 8; ++kk) {
            float4 zv = *(const float4*)&zsh[kk][b * 16 + ul * 4];
            z[0] += zv.x; z[1] += zv.y; z[2] += zv.z; z[3] += zv.w;
        }
        int idx = b * 2048 + myu;
        float co = c[idx];
        float ho = H[((size_t)(t - 1) * 16 + b) * 2048 + myu];
        float cn = sigmoidf_(z[1]) * co + sigmoidf_(z[0]) * tanhf(z[2]);
        float hn = sigmoidf_(z[3]) * tanhf(cn);
        int tok = token_of(ip[b * LAT + t]);
        float hw = tok != 0 ? hn : ho;
        float cw = tok != 0 ? cn : co;
        c[idx] = cw;
        H[((size_t)t * 16 + b) * 2048 + myu] = hw;
        u16 own = to_bf16(hw);
        int pair = __shfl_xor((int)own, 1);
        if (!(ul & 1)) {
            u32 val = (u32)own | ((u32)(u16)pair << 16);
            int k0 = myu >> 5, lg = (myu >> 3) & 3, i = myu & 7;
            *((u32*)hAout + ((((k0 * 64) + lg * 16 + b) * 8 + i) >> 1)) = val;
        }
    }
}

// ---- K4: softmax of all 128 recorded h rows -> d_out[b][t][:] ----
__global__ __launch_bounds__(256) void k_softmax(const float* __restrict__ H,
                                                 float* __restrict__ out) {
    int r = blockIdx.x;          // r = t*16 + b
    int t = r >> 4, b = r & 15;
    int tid = threadIdx.x;
    const float* hr = H + (size_t)r * VOCAB;
    float v[8];
    float m = -1e30f;
    #pragma unroll
    for (int i = 0; i < 8; ++i) { v[i] = hr[tid + i * 256]; m = fmaxf(m, v[i]); }

    __shared__ float redm[4], reds[4];
    int wid = tid >> 6, lane = tid & 63;
    #pragma unroll
    for (int off = 32; off; off >>= 1) m = fmaxf(m, __shfl_down(m, off));
    if (lane == 0) redm[wid] = m;
    __syncthreads();
    m = fmaxf(fmaxf(redm[0], redm[1]), fmaxf(redm[2], redm[3]));

    float e[8];
    float s = 0.0f;
    #pragma unroll
    for (int i = 0; i < 8; ++i) { e[i] = expf(v[i] - m); s += e[i]; }
    #pragma unroll
    for (int off = 32; off; off >>= 1) s += __shfl_down(s, off);
    if (lane == 0) reds[wid] = s;
    __syncthreads();
    s = reds[0] + reds[1] + reds[2] + reds[3];

    float* o = out + ((size_t)b * MAXLEN + t) * VOCAB;
    #pragma unroll
    for (int i = 0; i < 8; ++i) o[tid + i * 256] = e[i] / s;
}

extern "C" void kernel_launch(void* const* d_in, const int* in_sizes, int n_in,
                              void* d_out, int out_size, void* d_ws, size_t ws_size,
                              hipStream_t stream) {
    const float* ip = (const float*)d_in[0];   // (16,16)
    const float* E  = (const float*)d_in[1];   // (2048,256)
    const float* Wk = (const float*)d_in[2];   // (256,8192)
    const float* Wr = (const float*)d_in[3];   // (2048,8192)
    const float* bv = (const float*)d_in[4];   // (8192,)

    char* w = (char*)d_ws;
    float* xz  = (float*)w;  w += (size_t)8 * 512 * 16 * 16 * 4;       // 4 MB
    float* H   = (float*)w;  w += (size_t)262144 * 4;                  // 1 MB
    float* c   = (float*)w;  w += (size_t)32768 * 4;                   // 128 KB
    u16* XA  = (u16*)w;      w += (size_t)32768 * 2;                   // 64 KB
    u16* hA0 = (u16*)w;      w += (size_t)32768 * 2;
    u16* hA1 = (u16*)w;      w += (size_t)32768 * 2;
    u16* BWk = (u16*)w;      w += (size_t)2097152 * 2;                 // 4 MB
    u16* BW  = (u16*)w;      w += (size_t)16777216 * 2;                // 32 MB

    k_pack<<<4624, 256, 0, stream>>>(Wr, Wk, ip, E, BW, BWk, XA);
    k_xzmm0<<<512, 256, 0, stream>>>(BWk, XA, bv, ip, xz, H, c, hA1);
    u16* hAbuf[2] = {hA0, hA1};
    for (int t = 1; t < MAXLEN; ++t)
        k_step<<<512, 512, 0, stream>>>(BW, hAbuf[t & 1], hAbuf[(t + 1) & 1],
                                        xz, ip, c, H, t);
    k_softmax<<<128, 256, 0, stream>>>(H, (float*)d_out);
}